// Round 20
// baseline (1034.519 us; speedup 1.0000x reference)
//
#include <hip/hip_runtime.h>
#include <math.h>

#define BS   256
#define NN   255
#define DIM  128
#define GAMMA 0.07
#define NUM_ITERS 1000

__device__ __forceinline__ double wred_d(double v) {
  #pragma unroll
  for (int k = 1; k < 64; k <<= 1) v += __shfl_xor(v, k, 64);
  return v;
}
__device__ __forceinline__ int wred_i(int v) {
  #pragma unroll
  for (int k = 1; k < 64; k <<= 1) v += __shfl_xor(v, k, 64);
  return v;
}

// lane-uniform float readlane
__device__ __forceinline__ float RLF(float v, int lane) {
  return __int_as_float(__builtin_amdgcn_readlane(__float_as_int(v), lane));
}

// DPP wave64 sum -> total broadcast via readlane(63). VALU-only.
template <int CTRL, int RMASK>
__device__ __forceinline__ float dpp_add(float x) {
  int t = __builtin_amdgcn_update_dpp(0, __float_as_int(x), CTRL, RMASK, 0xf, true);
  return x + __int_as_float(t);
}
__device__ __forceinline__ float wred64_dpp(float x) {
  x = dpp_add<0x111, 0xf>(x);   // row_shr:1
  x = dpp_add<0x112, 0xf>(x);   // row_shr:2
  x = dpp_add<0x114, 0xf>(x);   // row_shr:4
  x = dpp_add<0x118, 0xf>(x);   // row_shr:8
  x = dpp_add<0x142, 0xa>(x);   // row_bcast:15
  x = dpp_add<0x143, 0xc>(x);   // row_bcast:31; lane63 = total
  return RLF(x, 63);
}

// fast reciprocal-sqrt: v_rsq_f32 + one Newton step (~0.5 ulp)
__device__ __forceinline__ float rsq_nr(float x) {
  float r;
  asm("v_rsq_f32 %0, %1" : "=v"(r) : "v"(x));
  r = r * (1.5f - 0.5f * x * r * r);
  return r;
}

// ---------------- kernel 1: normalized features, stored transposed fp64 ----------------
__global__ void k_ftr(const float* __restrict__ z, double* __restrict__ ftrT) {
  int b = blockIdx.x;
  int d = threadIdx.x;
  double z0 = (double)z[b * 256 + d];
  double z1 = (double)z[b * 256 + 128 + d];
  double n = sqrt(z0 * z0 + z1 * z1);
  n = fmax(n, 1e-12);
  ftrT[d * 512 + b]       = z0 / n;
  ftrT[d * 512 + 256 + b] = z1 / n;
}

// ---------------- kernel 2: K = exp(-gamma * dist), fp64 math, fp32 store ----------------
__global__ void k_K(const double* __restrict__ ftrT, float* __restrict__ K,
                    double* __restrict__ pk_knt, double* __restrict__ pos_arr) {
  int i = blockIdx.x;
  int t = threadIdx.x;
  __shared__ double rowi[DIM];
  __shared__ double redd[4];
  if (t < DIM) rowi[t] = ftrT[t * 512 + i];
  __syncthreads();
  double xn = 0.0;
  #pragma unroll 8
  for (int d = 0; d < DIM; ++d) xn += rowi[d] * rowi[d];

  double knt_part = 0.0;
  #pragma unroll
  for (int h = 0; h < 2; ++h) {
    int j = t + h * 256;
    double dot = 0.0, sq = 0.0;
    #pragma unroll 8
    for (int d = 0; d < DIM; ++d) {
      double f = ftrT[d * 512 + j];
      dot += rowi[d] * f;
      sq  += f * f;
    }
    double dist = xn + sq - 2.0 * dot;
    double kv = exp(-GAMMA * dist);
    K[i * 512 + j] = (float)kv;
    if (h == 1) {
      if (j == 256 + i) pos_arr[i] = kv;
      else knt_part += kv;
    }
  }
  double w = wred_d(knt_part);
  if ((t & 63) == 0) redd[t >> 6] = w;
  __syncthreads();
  if (t == 0) pk_knt[i] = redd[0] + redd[1] + redd[2] + redd[3];
}

// ---------------- kernel 3: per-batch PGD — PARTITIONED region2 ----------------
// 8 waves (512 thr). Wave rg: matvec rows [32rg,32rg+32) (kq[32] float4, as
// R16) AND state cols [32rg,32rg+32) — one col per lane (l<32). Bands match,
// so each wave reads the y-slice IT wrote (own-wave LDS dep, no 3rd barrier).
// Phase B is split into two short ALL-WAVE phases (the serial wave0 phase —
// ~450 cyc with 7 waves parked in R16 — is gone):
//   Bp1: 4 part loads/lane (half-wave splits bands; 2-way conflict is free),
//        shfl combine, redundant 8-lane gr, g (masked at a==r), n2 partial
//        via DPP -> n2p[rg].   B2.
//   Bp2: sum n2p (broadcast b128), rsq+NR, update own cols, write ytil slice
//        + Sp[rg] (next iter's S, read in next Bp1).
__global__ __launch_bounds__(512, 1) void k_pgd(
    const float* __restrict__ K, const float* __restrict__ alpha_init,
    double* __restrict__ neg_arr, double* __restrict__ sa_arr,
    int* __restrict__ cnt1, int* __restrict__ cntp, int* __restrict__ cnt0) {
  int r = blockIdx.x;
  int tid = threadIdx.x;
  int l = tid & 63;
  int rg = tid >> 6;        // 0..7 = band (32 rows / 32 state cols)

  __shared__ __align__(16) float ytil[BS];        // a-indexed, ytil[r]==0 always
  __shared__ __align__(16) float part[8][264];    // padded rows (bank-spread)
  __shared__ __align__(16) float Sp[8];           // per-wave y-sum partials
  __shared__ __align__(16) float n2p[8];          // per-wave n2 partials
  __shared__ float betat[1024];
  __shared__ double eNL[8], eSA[8];
  __shared__ int eC1[8], eCP[8], eCZ[8];

  // beta table: betat[i] = i/(i+3) fp32 (read at index it+1)
  for (int i = tid; i < 1024; i += 512)
    betat[i] = (float)i / ((float)i + 3.0f);

  // stage K block: rows 32rg+j, cols 4l..4l+3 (R16-identical)
  float4 kq[32];
  #pragma unroll
  for (int j = 0; j < 32; ++j)
    kq[j] = *(const float4*)&K[(32 * rg + j) * 512 + 4 * l];
  #pragma unroll
  for (int j = 0; j < 32; ++j)
    asm volatile("" : "+v"(kq[j].x), "+v"(kq[j].y), "+v"(kq[j].z), "+v"(kq[j].w));

  // partitioned state: lane l<32 of wave rg owns a-col a = 32rg + l
  int a = 32 * rg + l;               // meaningful for l<32
  float alS = 0.f, apS = 0.f, yvS = 0.f, kvS = 0.f, m = 0.f;
  if (l < 32) {
    if (a != r) {
      int c = a - (a > r ? 1 : 0);
      float v = alpha_init[r * NN + c];
      v = fminf(fmaxf(v, 0.f), 1.f);
      alS = v; apS = v; yvS = v;
      kvS = 1.0f - K[r * 512 + a];
      m = 1.f;
    }
    ytil[a] = yvS;                   // slot r gets 0
  }
  {
    float ys = wred64_dpp(yvS);      // upper lanes contribute 0
    if (l == 0) Sp[rg] = ys;
  }
  __syncthreads();                   // state + betat + ytil + Sp visible

  for (int it = 0; it < NUM_ITERS; ++it) {
    float beta = betat[it + 1];      // prefetch; consumed in Bp2

    // ---- phase A: band matvec (R16-identical) ----
    const float4* yb = (const float4*)&ytil[32 * rg];
    float4 acc = {0.f, 0.f, 0.f, 0.f};
    #pragma unroll
    for (int jj = 0; jj < 8; ++jj) {
      float4 yq = yb[jj];                      // wave-broadcast b128 (own slice)
      float4 k0 = kq[4 * jj + 0], k1 = kq[4 * jj + 1];
      float4 k2 = kq[4 * jj + 2], k3 = kq[4 * jj + 3];
      acc.x = fmaf(k0.x, yq.x, acc.x); acc.y = fmaf(k0.y, yq.x, acc.y);
      acc.z = fmaf(k0.z, yq.x, acc.z); acc.w = fmaf(k0.w, yq.x, acc.w);
      acc.x = fmaf(k1.x, yq.y, acc.x); acc.y = fmaf(k1.y, yq.y, acc.y);
      acc.z = fmaf(k1.z, yq.y, acc.z); acc.w = fmaf(k1.w, yq.y, acc.w);
      acc.x = fmaf(k2.x, yq.z, acc.x); acc.y = fmaf(k2.y, yq.z, acc.y);
      acc.z = fmaf(k2.z, yq.z, acc.z); acc.w = fmaf(k2.w, yq.z, acc.w);
      acc.x = fmaf(k3.x, yq.w, acc.x); acc.y = fmaf(k3.y, yq.w, acc.y);
      acc.z = fmaf(k3.z, yq.w, acc.z); acc.w = fmaf(k3.w, yq.w, acc.w);
    }
    *(float4*)&part[rg][4 * l] = acc;          // conflict-free b128 write
    __syncthreads();                           // B1: partials visible

    // ---- Bp1 (all waves): column sums + g + n2 partial for own band ----
    int cc = 32 * rg + (l & 31);
    int b0 = (l >> 5) * 4;                     // lanes 0-31: bands 0-3; 32-63: 4-7
    float s01 = part[b0 + 0][cc] + part[b0 + 1][cc];
    float s23 = part[b0 + 2][cc] + part[b0 + 3][cc];
    float gh = s01 + s23;
    float gA = gh + __shfl_down(gh, 32, 64);   // lanes 0-31: full column sum

    float grp = (l < 8) ? part[l][r] : 0.f;    // redundant per-wave gr
    grp += __shfl_down(grp, 4, 64);
    grp += __shfl_down(grp, 2, 64);
    grp += __shfl_down(grp, 1, 64);
    float gr = RLF(grp, 0);

    float4 sA = *(const float4*)&Sp[0];        // broadcast reads
    float4 sB = *(const float4*)&Sp[4];
    float S = ((sA.x + sA.y) + (sA.z + sA.w)) + ((sB.x + sB.y) + (sB.z + sB.w));

    // masked gradient (m=0 for a==r lane and all l>=32)
    float g = ((gA - gr) - 2.0f * m + kvS * S + 0.1f * yvS) * m;
    float n2part = wred64_dpp(g * g);
    if (l == 0) n2p[rg] = n2part;
    __syncthreads();                           // B2: n2 partials visible

    // ---- Bp2 (all waves): global norm + update own cols ----
    float4 nA = *(const float4*)&n2p[0];
    float4 nB = *(const float4*)&n2p[4];
    float n2 = ((nA.x + nA.y) + (nA.z + nA.w)) + ((nB.x + nB.y) + (nB.z + nB.w));
    float sinv = 0.001f * rsq_nr(n2);
    float na = fminf(fmaxf(fmaf(-sinv, g, yvS), 0.f), 1.f);  // masked lanes: 0
    apS = alS; alS = na;
    yvS = fmaf(beta, na - apS, na);
    if (l < 32) ytil[a] = yvS;                 // own slice; next A reads it (no barrier)
    float ys = wred64_dpp(yvS);
    if (l == 0) Sp[rg] = ys;
    // no B3: next phase A reads only this wave's own ytil slice; part reads
    // (Bp1) are fenced from next phase-A writes by B2 + B1.
  }

  // ---- epilogue: partitioned fp64/count reductions ----
  {
    double nl = 0.0, sa = 0.0;
    int c1 = 0, cp = 0, cz = 0;
    if (l < 32 && a != r) {
      float kx = K[a * 512 + 256 + r];         // KnT[r, c(a)]
      nl = (double)alS * (double)kx;
      sa = (double)alS;
      c1 = (alS == 1.0f);
      cp = (alS > 0.0f);
      cz = (alS == 0.0f);
    }
    nl = wred_d(nl); sa = wred_d(sa);
    c1 = wred_i(c1); cp = wred_i(cp); cz = wred_i(cz);
    if (l == 0) { eNL[rg] = nl; eSA[rg] = sa; eC1[rg] = c1; eCP[rg] = cp; eCZ[rg] = cz; }
  }
  __syncthreads();
  if (tid == 0) {
    double nlS = 0.0, saS = 0.0; int c1S = 0, cpS = 0, czS = 0;
    #pragma unroll
    for (int k = 0; k < 8; ++k) {
      nlS += eNL[k]; saS += eSA[k];
      c1S += eC1[k]; cpS += eCP[k]; czS += eCZ[k];
    }
    neg_arr[r] = nlS;
    sa_arr[r]  = saS;
    cnt1[r] = c1S; cntp[r] = cpS; cnt0[r] = czS;
  }
}

// ---------------- kernel 4: final reduction to the 6 scalar outputs ----------------
__global__ void k_fin(const double* __restrict__ pk_knt, const double* __restrict__ pos_arr,
                      const double* __restrict__ neg_arr, const double* __restrict__ sa_arr,
                      const int* __restrict__ cnt1, const int* __restrict__ cntp,
                      const int* __restrict__ cnt0, float* __restrict__ out) {
  int t = threadIdx.x;  // 256
  __shared__ double rd[16];
  __shared__ int ri[12];
  double knt = pk_knt[t];
  double pos = pos_arr[t];
  double neg = neg_arr[t];
  double pl  = sa_arr[t] * pos_arr[t];
  int a1 = cnt1[t], ap = cntp[t], a0 = cnt0[t];
  knt = wred_d(knt); pos = wred_d(pos); neg = wred_d(neg); pl = wred_d(pl);
  a1 = wred_i(a1); ap = wred_i(ap); a0 = wred_i(a0);
  int w = t >> 6;
  if ((t & 63) == 0) {
    rd[w] = knt; rd[4 + w] = pos; rd[8 + w] = neg; rd[12 + w] = pl;
    ri[w] = a1; ri[4 + w] = ap; ri[8 + w] = a0;
  }
  __syncthreads();
  if (t == 0) {
    double kntS = rd[0] + rd[1] + rd[2] + rd[3];
    double posS = rd[4] + rd[5] + rd[6] + rd[7];
    double negS = rd[8] + rd[9] + rd[10] + rd[11];
    double plS  = rd[12] + rd[13] + rd[14] + rd[15];
    int c1t = ri[0] + ri[1] + ri[2] + ri[3];
    int cpt = ri[4] + ri[5] + ri[6] + ri[7];
    int c0t = ri[8] + ri[9] + ri[10] + ri[11];
    out[0] = (float)(negS / 256.0 - plS / 256.0);
    out[1] = (float)(posS / 256.0);
    out[2] = (float)(kntS / (256.0 * 255.0));
    out[3] = (float)c1t / ((float)cpt + 1e-10f);
    out[4] = (float)c0t / 65280.0f;
    out[5] = 0.0f;
  }
}

extern "C" void kernel_launch(void* const* d_in, const int* in_sizes, int n_in,
                              void* d_out, int out_size, void* d_ws, size_t ws_size,
                              hipStream_t stream) {
  const float* z     = (const float*)d_in[0];
  const float* ainit = (const float*)d_in[1];
  char* ws = (char*)d_ws;
  double* ftrT   = (double*)ws;                       // 512 KB
  float*  K      = (float*)(ws + 524288);             // 512 KB
  double* pk_knt = (double*)(ws + 1048576);
  double* pos_a  = (double*)(ws + 1048576 + 2048);
  double* neg_a  = (double*)(ws + 1048576 + 4096);
  double* sa_a   = (double*)(ws + 1048576 + 6144);
  int* cnt1 = (int*)(ws + 1048576 + 8192);
  int* cntp = (int*)(ws + 1048576 + 8192 + 1024);
  int* cnt0 = (int*)(ws + 1048576 + 8192 + 2048);
  float* out = (float*)d_out;

  k_ftr<<<256, 128, 0, stream>>>(z, ftrT);
  k_K  <<<256, 256, 0, stream>>>(ftrT, K, pk_knt, pos_a);
  k_pgd<<<256, 512, 0, stream>>>(K, ainit, neg_a, sa_a, cnt1, cntp, cnt0);
  k_fin<<<1, 256, 0, stream>>>(pk_knt, pos_a, neg_a, sa_a, cnt1, cntp, cnt0, out);
}